// Round 2
// baseline (2740.884 us; speedup 1.0000x reference)
//
#include <hip/hip_runtime.h>

// Eikonal 3D — 288 Jacobi-parallel Godunov sweeps on a 96^3 grid.
// Round 2: float4 vectorization, 4 k-cells per thread.
// Ping-pong: A = d_out, B = d_ws. 288 steps (even) -> final lands in d_out.

#define N    96
#define N2   (96 * 96)
#define N3   (96 * 96 * 96)
#define NQ   (N3 / 4)          // quads of 4 k-cells
#define QROW (N / 4)           // 24 quads per k-row
#define BIGV 1e5f
#define SRC_IDX (48 * N2 + 48 * N + 48)

__global__ __launch_bounds__(256) void eik_init(float* __restrict__ u) {
    int idx = blockIdx.x * 256 + threadIdx.x;
    u[idx] = (idx == SRC_IDX) ? 0.0f : BIGV;
}

__device__ __forceinline__ float godunov_cell(float a, float b, float c,
                                              float fh, float uc) {
    float lo  = fminf(fminf(a, b), c);
    float hi  = fmaxf(fmaxf(a, b), c);
    float mid = a + b + c - lo - hi;

    float u1 = lo + fh;

    float dlm = lo - mid;
    float d2  = 2.0f * fh * fh - dlm * dlm;
    float u2  = (d2 > 0.0f) ? 0.5f * (lo + mid + sqrtf(d2)) : BIGV;

    float s  = lo + mid + hi;
    float q  = lo * lo + mid * mid + hi * hi - fh * fh;
    float d3 = s * s - 3.0f * q;
    float u3 = (d3 > 0.0f) ? (s + sqrtf(d3)) / 3.0f : BIGV;

    float cand = (u1 <= mid) ? u1 : ((u2 <= hi) ? u2 : u3);
    return fminf(uc, cand);
}

__global__ __launch_bounds__(256) void eik_step4(const float* __restrict__ u,
                                                 const float* __restrict__ f,
                                                 float* __restrict__ un) {
    int q = blockIdx.x * 256 + threadIdx.x;   // quad index, [0, NQ)
    int k0 = (q % QROW) * 4;
    int t  = q / QROW;
    int j  = t % N;
    int i  = t / N;
    int base = i * N2 + j * N + k0;           // 16B-aligned (k0 % 4 == 0)

    const float4 BIG4 = make_float4(BIGV, BIGV, BIGV, BIGV);

    float4 uc = *reinterpret_cast<const float4*>(u + base);
    float4 xm = (i > 0)     ? *reinterpret_cast<const float4*>(u + base - N2) : BIG4;
    float4 xp = (i < N - 1) ? *reinterpret_cast<const float4*>(u + base + N2) : BIG4;
    float4 ym = (j > 0)     ? *reinterpret_cast<const float4*>(u + base - N)  : BIG4;
    float4 yp = (j < N - 1) ? *reinterpret_cast<const float4*>(u + base + N)  : BIG4;
    float  zl = (k0 > 0)      ? u[base - 1] : BIGV;
    float  zr = (k0 < N - 4)  ? u[base + 4] : BIGV;
    float4 f4 = *reinterpret_cast<const float4*>(f + base);

    // per-cell axis minima
    float ax, bx, cx;
    float4 un4;

    // cell 0
    ax = fminf(xm.x, xp.x);
    bx = fminf(ym.x, yp.x);
    cx = fminf(zl,   uc.y);
    un4.x = godunov_cell(ax, bx, cx, f4.x, uc.x);
    // cell 1
    ax = fminf(xm.y, xp.y);
    bx = fminf(ym.y, yp.y);
    cx = fminf(uc.x, uc.z);
    un4.y = godunov_cell(ax, bx, cx, f4.y, uc.y);
    // cell 2
    ax = fminf(xm.z, xp.z);
    bx = fminf(ym.z, yp.z);
    cx = fminf(uc.y, uc.w);
    un4.z = godunov_cell(ax, bx, cx, f4.z, uc.z);
    // cell 3
    ax = fminf(xm.w, xp.w);
    bx = fminf(ym.w, yp.w);
    cx = fminf(uc.z, zr);
    un4.w = godunov_cell(ax, bx, cx, f4.w, uc.w);

    if (base == SRC_IDX) un4.x = 0.0f;        // src at k=48, k0=48 lane .x
    *reinterpret_cast<float4*>(un + base) = un4;
}

extern "C" void kernel_launch(void* const* d_in, const int* in_sizes, int n_in,
                              void* d_out, int out_size, void* d_ws, size_t ws_size,
                              hipStream_t stream) {
    const float* f = (const float*)d_in[0];
    float* A = (float*)d_out;   // even-iteration source / final result
    float* B = (float*)d_ws;    // odd-iteration buffer

    eik_init<<<N3 / 256, 256, 0, stream>>>(A);

    const int nblk = NQ / 256;  // 864
    for (int it = 0; it < 288; ++it) {
        const float* src = (it & 1) ? B : A;
        float*       dst = (it & 1) ? A : B;
        eik_step4<<<nblk, 256, 0, stream>>>(src, f, dst);
    }
    // it=287 writes A == d_out
}